// Round 1
// baseline (184.586 us; speedup 1.0000x reference)
//
#include <hip/hip_runtime.h>

// 3x3 median blur + residual: out = x + 0.2*(med3x3(x) - x), zero padding.
// Memory-bound: 201 MB total traffic -> ~32 us floor @ 6.3 TB/s.

#define S2(a, b) { float _t = fminf(a, b); b = fmaxf(a, b); a = _t; }

__device__ __forceinline__ float med3f(float a, float b, float c) {
    // median of 3 = max(min(a,b), min(max(a,b), c))
    return fmaxf(fminf(a, b), fminf(fmaxf(a, b), c));
}

__global__ __launch_bounds__(256) void median_blur_kernel(
    const float* __restrict__ xin, float* __restrict__ out, int H, int W)
{
    const int tx = threadIdx.x;      // 0..255
    const int x0 = tx << 2;          // 4 px per thread, float4-aligned
    const int y  = blockIdx.x;       // row
    const int z  = blockIdx.y;       // plane (B*C)
    const size_t plane = (size_t)z * H * W;
    const float* base = xin + plane;

    float t[6], m[6], b[6];

    // mid row (always valid)
    {
        const float* row = base + (size_t)y * W;
        const float4 c = *reinterpret_cast<const float4*>(row + x0);
        m[0] = (x0 > 0)     ? row[x0 - 1] : 0.0f;
        m[1] = c.x; m[2] = c.y; m[3] = c.z; m[4] = c.w;
        m[5] = (x0 + 4 < W) ? row[x0 + 4] : 0.0f;
    }
    // top row (zero pad at y==0)
    if (y > 0) {
        const float* row = base + (size_t)(y - 1) * W;
        const float4 c = *reinterpret_cast<const float4*>(row + x0);
        t[0] = (x0 > 0)     ? row[x0 - 1] : 0.0f;
        t[1] = c.x; t[2] = c.y; t[3] = c.z; t[4] = c.w;
        t[5] = (x0 + 4 < W) ? row[x0 + 4] : 0.0f;
    } else {
        t[0] = t[1] = t[2] = t[3] = t[4] = t[5] = 0.0f;
    }
    // bottom row (zero pad at y==H-1)
    if (y + 1 < H) {
        const float* row = base + (size_t)(y + 1) * W;
        const float4 c = *reinterpret_cast<const float4*>(row + x0);
        b[0] = (x0 > 0)     ? row[x0 - 1] : 0.0f;
        b[1] = c.x; b[2] = c.y; b[3] = c.z; b[4] = c.w;
        b[5] = (x0 + 4 < W) ? row[x0 + 4] : 0.0f;
    } else {
        b[0] = b[1] = b[2] = b[3] = b[4] = b[5] = 0.0f;
    }

    // originals of the 4 center pixels (mid row) for the residual
    const float origs[4] = { m[1], m[2], m[3], m[4] };

    // sort each of the 6 columns vertically: lo <= mi <= hi
    float lo[6], mi[6], hi[6];
#pragma unroll
    for (int j = 0; j < 6; ++j) {
        float a = t[j], c0 = m[j], d = b[j];
        S2(a, c0); S2(c0, d); S2(a, c0);
        lo[j] = a; mi[j] = c0; hi[j] = d;
    }

    // median of 9 = med3( max of column-mins, med of column-meds, min of column-maxes )
    float4 o;
    float* op = &o.x;
#pragma unroll
    for (int j = 0; j < 4; ++j) {
        float mxlo = fmaxf(lo[j], fmaxf(lo[j + 1], lo[j + 2]));
        float mnhi = fminf(hi[j], fminf(hi[j + 1], hi[j + 2]));
        float mdmi = med3f(mi[j], mi[j + 1], mi[j + 2]);
        float med  = med3f(mxlo, mdmi, mnhi);
        float xc   = origs[j];
        op[j] = xc + 0.2f * (med - xc);
    }
    *reinterpret_cast<float4*>(out + plane + (size_t)y * W + x0) = o;
}

extern "C" void kernel_launch(void* const* d_in, const int* in_sizes, int n_in,
                              void* d_out, int out_size, void* d_ws, size_t ws_size,
                              hipStream_t stream) {
    const float* x = (const float*)d_in[0];
    float* out = (float*)d_out;
    const int H = 1024, W = 1024;
    const int planes = in_sizes[0] / (H * W);   // B*C = 24
    dim3 block(256);                             // 256 threads x 4 px = one full row
    dim3 grid(H, planes);
    median_blur_kernel<<<grid, block, 0, stream>>>(x, out, H, W);
}

// Round 2
// 182.095 us; speedup vs baseline: 1.0137x; 1.0137x over previous
//
#include <hip/hip_runtime.h>

// 3x3 median blur + residual, zero padding, x:(8,3,1024,1024) f32.
// Sliding-window strip kernel: each block = 16 output rows x 1024 px.
// Reads 18 rows per 16 output rows (1.125x vertical fetch), halo via shfl.

#define S2(a, b) { float _t = fminf(a, b); b = fmaxf(a, b); a = _t; }

__device__ __forceinline__ float med3f(float a, float b, float c) {
    return fmaxf(fminf(a, b), fminf(fmaxf(a, b), c));
}

constexpr int ROWS = 16;   // output rows per block (1024 % 16 == 0)

__global__ __launch_bounds__(256) void median_blur_kernel(
    const float* __restrict__ xin, float* __restrict__ out)
{
    const int W = 1024, H = 1024;
    const int tx   = threadIdx.x;
    const int lane = tx & 63;
    const int x0   = tx << 2;              // 4 px per thread
    const int y0   = blockIdx.x * ROWS;    // first output row of this strip
    const int z    = blockIdx.y;           // plane (B*C = 24)
    const size_t plane = (size_t)z * H * W;
    const float* base  = xin + plane;
    float*       obase = out + plane;

    float t[6], m[6], b[6];

    // load one padded row: 4 center px via float4, halo via wave shuffle.
    auto load_row = [&](int y, float* dst) {
        if (y < 0 || y >= H) {             // zero padding rows (block-uniform branch)
#pragma unroll
            for (int j = 0; j < 6; ++j) dst[j] = 0.0f;
            return;
        }
        const float* row = base + (size_t)y * W;
        float4 c = *reinterpret_cast<const float4*>(row + x0);
        float left  = __shfl_up(c.w, 1);   // lane tx-1's last element
        float right = __shfl_down(c.x, 1); // lane tx+1's first element
        if (lane == 0)  left  = (x0 > 0)     ? row[x0 - 1] : 0.0f;
        if (lane == 63) right = (x0 + 4 < W) ? row[x0 + 4] : 0.0f;
        dst[0] = left; dst[1] = c.x; dst[2] = c.y; dst[3] = c.z; dst[4] = c.w; dst[5] = right;
    };

    load_row(y0 - 1, t);
    load_row(y0,     m);
    load_row(y0 + 1, b);

#pragma unroll 4
    for (int r = 0; r < ROWS; ++r) {
        // prefetch next bottom row (issued before compute; waitcnt lands after)
        float nxt[6];
        {
            const int yn = (r < ROWS - 1) ? (y0 + r + 2) : H;  // H -> zeros, no load
            load_row(yn, nxt);
        }

        // sort each of the 6 columns vertically
        float lo[6], mi[6], hi[6];
#pragma unroll
        for (int j = 0; j < 6; ++j) {
            float a = t[j], c0 = m[j], d = b[j];
            S2(a, c0); S2(c0, d); S2(a, c0);
            lo[j] = a; mi[j] = c0; hi[j] = d;
        }

        // median of 9 = med3(max of col-mins, med of col-meds, min of col-maxes)
        float4 o; float* op = &o.x;
#pragma unroll
        for (int j = 0; j < 4; ++j) {
            float mxlo = fmaxf(lo[j], fmaxf(lo[j + 1], lo[j + 2]));
            float mnhi = fminf(hi[j], fminf(hi[j + 1], hi[j + 2]));
            float mdmi = med3f(mi[j], mi[j + 1], mi[j + 2]);
            float med  = med3f(mxlo, mdmi, mnhi);
            float xc   = m[j + 1];
            op[j] = xc + 0.2f * (med - xc);
        }
        *reinterpret_cast<float4*>(obase + (size_t)(y0 + r) * W + x0) = o;

        // slide window down one row
#pragma unroll
        for (int j = 0; j < 6; ++j) { t[j] = m[j]; m[j] = b[j]; b[j] = nxt[j]; }
    }
}

extern "C" void kernel_launch(void* const* d_in, const int* in_sizes, int n_in,
                              void* d_out, int out_size, void* d_ws, size_t ws_size,
                              hipStream_t stream) {
    const float* x = (const float*)d_in[0];
    float* out = (float*)d_out;
    const int H = 1024, W = 1024;
    const int planes = in_sizes[0] / (H * W);   // 24
    dim3 block(256);
    dim3 grid(H / ROWS, planes);                // 64 strips x 24 planes = 1536 blocks
    median_blur_kernel<<<grid, block, 0, stream>>>(x, out);
}